// Round 6
// baseline (488.785 us; speedup 1.0000x reference)
//
#include <hip/hip_runtime.h>

typedef float v2f __attribute__((ext_vector_type(2)));

#define HH 192
#define WW 192
#define BATCH 16
#define PLANE (HH*WW)              /* 36864 */
#define NELEM (BATCH*2*PLANE)      /* 1179648 */

// Tile: 96 px wide x 8 rows, 256 threads, 3 px per thread. Halo 2 each side.
// Grid = (2,24,16) = 768 blocks = exactly 3 blocks/CU at launch_bounds(256,3)
// -> all blocks co-resident (proven: R3 mega's global barrier completed).
#define TILEX 96
#define TILEY 8
#define SW 100  /* TILEX + 4 */
#define SH2 12  /* TILEY + 4 */
#define NSITE (SH2*SW)   /* 1200 sites, both channels per site */
#define NTILES 768       /* 2 * 24 * 16 */
#define DTF 0.2f
#define DTH 0.1f

// Workspace float offsets:
//   0..200    K8T conv weights (tap-major [25][8])
//   256..414  PP packed poly weight pairs (79 v2f {k=0,k=1})
//   512..     flags: 9 rows x 768 tiles (u32), zeroed by prep each replay
//   8192..    P0, P1 ping-pong buffers, SITE-INTERLEAVED v2f {ch0,ch1}
#define WS_PP    256
#define WS_FLAGS 512
#define WS_BUF   8192

__global__ void prep_kernel(const float* __restrict__ kern,
                            const float* __restrict__ pw0, const float* __restrict__ pb0,
                            const float* __restrict__ pw1, const float* __restrict__ pb1,
                            const float* __restrict__ pwf, const float* __restrict__ pbf,
                            float* __restrict__ ws)
{
    int t = blockIdx.x * blockDim.x + threadIdx.x;
    if (t < 200) {
        const float inv  = 1.0f / 0.0327249f;
        const float inv2 = inv * inv;
        const float sc[6] = {1.0f, inv, inv, inv2, inv2, inv2};
        int o = t / 8, j = t % 8, dy = o / 5, dx = o % 5;
        float v;
        if (j < 6)       v =  kern[j*25 + dy*5 + dx] * sc[j];
        else if (j == 6) v = -kern[1*25 + dy*5 + (4-dx)] * sc[1];
        else             v = -kern[2*25 + (4-dy)*5 + dx] * sc[2];
        ws[o*8 + j] = v;
    } else if (t < 279) {
        int p = t - 200;
        int arr, a, b;
        if (p < 12)       { arr=0; a=p;      b=24+p; }
        else if (p < 24)  { int i=p-12; arr=0; a=12+i; b=36+i; }
        else if (p == 24) { arr=1; a=0; b=2; }
        else if (p == 25) { arr=1; a=1; b=3; }
        else if (p < 38)  { int i=p-26; arr=2; a=i;    b=26+i; }
        else if (p < 50)  { int i=p-38; arr=2; a=13+i; b=39+i; }
        else if (p == 50) { arr=2; a=12; b=38; }
        else if (p == 51) { arr=2; a=25; b=51; }
        else if (p == 52) { arr=3; a=0; b=2; }
        else if (p == 53) { arr=3; a=1; b=3; }
        else if (p < 68)  { int i=p-54; arr=4; a=i; b=14+i; }
        else if (p == 68) { arr=5; a=0; b=1; }
        else {
            const signed char   A0[10] = {1,2,13,14,1,2,14,15,1,2};
            const signed char   A1[10] = {31,32,43,44,33,34,46,47,21,22};
            const unsigned char AR[10] = {0,0,0,0,2,2,2,2,4,4};
            int i = p - 69; arr = AR[i]; a = A0[i]; b = A1[i];
        }
        const float* bases[6] = {pw0, pb0, pw1, pb1, pwf, pbf};
        v2f v; v[0] = bases[arr][a]; v[1] = bases[arr][b];
        ((v2f*)(ws + WS_PP))[p] = v;
    }
    // Zero the producer-consumer flags (workspace is poisoned each iteration).
    unsigned* flags = (unsigned*)(ws + WS_FLAGS);
    for (int i = t; i < 9 * NTILES; i += 320) flags[i] = 0u;
}

union DV { double d; v2f v; };

// All 10 RHS evals in ONE kernel. Inter-eval coherence WITHOUT barriers or
// cache writebacks: ping-pong data + flags use agent-scope relaxed atomics
// (sc1 -> Infinity Cache is the coherence point; L1/L2 never hold this data).
// Sync is per-tile: each block waits only on the 6 neighbor tiles (3 rows x
// 2 cols; halo=2 <= tile dims) of the previous eval. Flag is set after a
// __syncthreads whose built-in vmcnt(0) drains all sc1 stores.
// ubase carried in registers (bit-exact vs re-reading). Compute section is
// byte-identical to the verified packed R5 kernel.
__global__ __launch_bounds__(256, 3) void mega_kernel(
    const float* __restrict__ init,
    float* __restrict__ out,
    float* __restrict__ ws)
{
    const float* K8T = ws;
    const v2f* PP = (const v2f*)(ws + WS_PP);
    unsigned* flags = (unsigned*)(ws + WS_FLAGS);
    v2f* P0 = (v2f*)(ws + WS_BUF);            // NELEM/2 sites
    v2f* P1 = P0 + (NELEM / 2);

    __shared__ v2f sh[SH2][SW];
    const int b   = blockIdx.z;
    const int bx  = blockIdx.x;               // 0..1
    const int by  = blockIdx.y;               // 0..23
    const int ty0 = by * TILEY;
    const int tx0 = bx * TILEX;
    const int tid = threadIdx.x;
    const int myflat = b * 48 + by * 2 + bx;

    const int cy = tid >> 5;            // 0..7
    const int x3 = (tid & 31) * 3;      // 0,3,..,93
    const int oy = ty0 + cy, ox = tx0 + x3;
    const size_t site0 = (size_t)b * PLANE + (size_t)oy * WW + ox;

    float base0[3], base1[3];

    #pragma unroll 1
    for (int s = 0; s < 10; ++s) {
        const float alpha = (s & 1) ? DTF : DTH;
        const v2f* Pr = (s & 1) ? P0 : P1;    // read buffer (s>=1)
        v2f*       Pw = (s & 1) ? P1 : P0;    // write buffer (s<9)

        // ---- Wait for the 6 producer tiles of eval s-1 (also fences sh reuse).
        if (s) {
            if (tid < 6) {
                int ny = by + (tid >> 1) - 1;
                if (ny < 0) ny += 24; else if (ny >= 24) ny -= 24;
                const int nc = (tid & 1) ? (1 - bx) : bx;
                const unsigned* f = flags + (s - 1) * NTILES + (b * 48 + ny * 2 + nc);
                while (!__hip_atomic_load(f, __ATOMIC_RELAXED, __HIP_MEMORY_SCOPE_AGENT))
                    __builtin_amdgcn_s_sleep(1);
            }
            __syncthreads();
        }

        // ---- Staging: 1200 sites, 5 iters/thread.
        if (s == 0) {
            const float* init_b = init + (size_t)b * 2 * PLANE;
            for (int i = tid; i < NSITE; i += 256) {
                const int ly  = i / SW;
                const int col = i - ly * SW;
                int gy = ty0 + ly - 2;  if (gy < 0) gy += HH; else if (gy >= HH) gy -= HH;
                int gx = tx0 + col - 2; if (gx < 0) gx += WW; else if (gx >= WW) gx -= WW;
                const int gi = gy*WW + gx;
                v2f v; v[0] = init_b[gi]; v[1] = init_b[PLANE + gi];
                sh[ly][col] = v;
            }
        } else {
            const v2f* Pb = Pr + (size_t)b * PLANE;
            for (int i = tid; i < NSITE; i += 256) {
                const int ly  = i / SW;
                const int col = i - ly * SW;
                int gy = ty0 + ly - 2;  if (gy < 0) gy += HH; else if (gy >= HH) gy -= HH;
                int gx = tx0 + col - 2; if (gx < 0) gx += WW; else if (gx >= WW) gx -= WW;
                DV cv;
                cv.d = __hip_atomic_load((const double*)(Pb + gy*WW + gx),
                                         __ATOMIC_RELAXED, __HIP_MEMORY_SCOPE_AGENT);
                sh[ly][col] = cv.v;
            }
        }
        __syncthreads();

        if (s == 0) {
            #pragma unroll
            for (int p = 0; p < 3; ++p) {
                const v2f v = sh[cy+2][x3+2+p];
                base0[p] = v[0]; base1[p] = v[1];
            }
        }

        // ---- Conv: D2[px][j] = v2f over channels. dy loop rolled.
        v2f D2[3][8];
        #pragma unroll
        for (int p = 0; p < 3; ++p)
            #pragma unroll
            for (int j = 0; j < 8; ++j)
                D2[p][j] = (v2f){0.0f, 0.0f};

        #pragma unroll 1
        for (int dy = 0; dy < 5; ++dy) {
            v2f row[7];
            #pragma unroll
            for (int dx = 0; dx < 7; ++dx)
                row[dx] = sh[cy + dy][x3 + dx];
            const float* Kt = K8T + dy * 40;
            #pragma unroll
            for (int dx = 0; dx < 5; ++dx) {
                #pragma unroll
                for (int j = 0; j < 8; ++j) {
                    const float w = Kt[dx*8 + j];
                    D2[0][j] += row[dx]   * w;
                    D2[1][j] += row[dx+1] * w;
                    D2[2][j] += row[dx+2] * w;
                }
            }
        }

#define Z(p,i) (D2[p][(i)%6][(i)/6])

        v2f res[3];
        #pragma unroll
        for (int p = 0; p < 3; ++p) {
            // Base pass, packed over k.
            v2f o0 = PP[24], o1 = PP[25];
            #pragma unroll
            for (int i = 0; i < 12; ++i) {
                const float zv = Z(p, i);
                o0 += PP[i]    * zv;
                o1 += PP[12+i] * zv;
            }
            const v2f pb = o0 * o1;
            v2f q0 = PP[52] + PP[50]*pb;
            v2f q1 = PP[53] + PP[51]*pb;
            #pragma unroll
            for (int i = 0; i < 12; ++i) {
                const float zv = Z(p, i);
                q0 += PP[26+i] * zv;
                q1 += PP[38+i] * zv;
            }

            // Gradients at the upwind-selectable features, packed over k.
            const v2f t1 = o1*PP[69] + o0*PP[71];
            const v2f g1 = PP[77] + PP[66]*t1
                + PP[67]*(q1*(PP[73] + PP[50]*t1) + q0*(PP[75] + PP[51]*t1));
            const v2f t2 = o1*PP[70] + o0*PP[72];
            const v2f g2 = PP[78] + PP[66]*t2
                + PP[67]*(q1*(PP[74] + PP[50]*t2) + q0*(PP[76] + PP[51]*t2));

            const float s1 = (g1[0] > 0.0f) ? Z(p,1) : D2[p][6][0];
            const float s2 = (g2[0] > 0.0f) ? Z(p,2) : D2[p][7][0];
            const float s3 = (g1[1] > 0.0f) ? Z(p,7) : D2[p][6][1];
            const float s4 = (g2[1] > 0.0f) ? Z(p,8) : D2[p][7][1];
#define XV(i) ((i)==1 ? s1 : (i)==2 ? s2 : (i)==7 ? s3 : (i)==8 ? s4 : Z(p,(i)))

            // Forward poly at selected features, packed over k.
            v2f f0 = PP[24], f1 = PP[25];
            #pragma unroll
            for (int i = 0; i < 12; ++i) {
                const float xv = XV(i);
                f0 += PP[i]    * xv;
                f1 += PP[12+i] * xv;
            }
            const v2f pf = f0 * f1;
            v2f r0 = PP[52] + PP[50]*pf;
            v2f r1 = PP[53] + PP[51]*pf;
            v2f y  = PP[68] + PP[66]*pf;
            #pragma unroll
            for (int i = 0; i < 12; ++i) {
                const float xv = XV(i);
                r0 += PP[26+i] * xv;
                r1 += PP[38+i] * xv;
                y  += PP[54+i] * xv;
            }
            res[p] = y + PP[67]*(r0*r1);
#undef XV
        }

        // ---- Write (sc1 to ping-pong, plain to final out) + carry base.
        if (s == 9) {
            const size_t o0i = (size_t)b * 2 * PLANE + (size_t)oy * WW + ox;
            #pragma unroll
            for (int p = 0; p < 3; ++p) {
                out[o0i + p]         = base0[p] + alpha * res[p][0];
                out[o0i + PLANE + p] = base1[p] + alpha * res[p][1];
            }
        } else {
            v2f* dst = Pw + site0;
            #pragma unroll
            for (int p = 0; p < 3; ++p) {
                const float w0v = base0[p] + alpha * res[p][0];
                const float w1v = base1[p] + alpha * res[p][1];
                DV cv; cv.v = (v2f){w0v, w1v};
                __hip_atomic_store((double*)(dst + p), cv.d,
                                   __ATOMIC_RELAXED, __HIP_MEMORY_SCOPE_AGENT);
                if (s & 1) { base0[p] = w0v; base1[p] = w1v; }
            }
            // Drain all waves' sc1 stores (pre-barrier vmcnt(0)), then publish.
            __syncthreads();
            if (tid == 0)
                __hip_atomic_store(flags + s * NTILES + myflat, 1u,
                                   __ATOMIC_RELAXED, __HIP_MEMORY_SCOPE_AGENT);
        }
    }
}

extern "C" void kernel_launch(void* const* d_in, const int* in_sizes, int n_in,
                              void* d_out, int out_size, void* d_ws, size_t ws_size,
                              hipStream_t stream)
{
    const float* init = (const float*)d_in[0];
    const float* kern = (const float*)d_in[1];
    const float* pw0  = (const float*)d_in[2];
    const float* pb0  = (const float*)d_in[3];
    const float* pw1  = (const float*)d_in[4];
    const float* pb1  = (const float*)d_in[5];
    const float* pwf  = (const float*)d_in[6];
    const float* pbf  = (const float*)d_in[7];
    float* out = (float*)d_out;
    float* ws  = (float*)d_ws;

    prep_kernel<<<dim3(1), dim3(320), 0, stream>>>(kern, pw0, pb0, pw1, pb1, pwf, pbf, ws);

    const dim3 grid(WW/TILEX, HH/TILEY, BATCH);   // (2, 24, 16) = 768 blocks
    mega_kernel<<<grid, dim3(256), 0, stream>>>(init, out, ws);
}

// Round 7
// 219.001 us; speedup vs baseline: 2.2319x; 2.2319x over previous
//
#include <hip/hip_runtime.h>

typedef float v2f __attribute__((ext_vector_type(2)));

#define HH 192
#define WW 192
#define BATCH 16
#define PLANE (HH*WW)              /* 36864 */
#define NELEM (BATCH*2*PLANE)      /* 1179648 */

// Tile: 32 px wide x 8 rows, 128 threads, 2 px per thread. Halo 2 each side.
// Grid = (6,24,16) = 2304 blocks = exactly 9 blocks/CU (18 waves/CU, 4.5/SIMD)
// -> 1.5x the occupancy of the 96x8/3px layout, perfect CU balance.
#define TILEX 32
#define TILEY 8
#define SW 36   /* TILEX + 4 */
#define SH2 12  /* TILEY + 4 */
#define NSITE (SH2*SW)   /* 432 sites, both channels per site */

// Workspace: [0..200) K8T conv weights (tap-major [25][8]);
// [256..414) PP packed poly weight PAIRS as v2f {k=0, k=1};
// bufA at ws+512, bufH after.
//
// PP index map (v2f units):
//  0..11  W0a[i]={pw0[i],pw0[24+i]}      12..23 W0b[i]={pw0[12+i],pw0[36+i]}
//  24 B0a={pb0[0],pb0[2]}  25 B0b={pb0[1],pb0[3]}
//  26..37 W1a[i]={pw1[i],pw1[26+i]}      38..49 W1b[i]={pw1[13+i],pw1[39+i]}
//  50 W112={pw1[12],pw1[38]}  51 W125={pw1[25],pw1[51]}
//  52 B1a={pb1[0],pb1[2]}  53 B1b={pb1[1],pb1[3]}
//  54..67 WF[i]={pwf[i],pwf[14+i]}  (66=WF12, 67=WF13)
//  68 BF={pbf[0],pbf[1]}
//  69,70 GW0a; 71,72 GW0b; 73,74 GW1a; 75,76 GW1b; 77,78 GWF
__global__ void prep_kernel(const float* __restrict__ kern,
                            const float* __restrict__ pw0, const float* __restrict__ pb0,
                            const float* __restrict__ pw1, const float* __restrict__ pb1,
                            const float* __restrict__ pwf, const float* __restrict__ pbf,
                            float* __restrict__ ws)
{
    int t = blockIdx.x * blockDim.x + threadIdx.x;
    if (t < 200) {
        const float inv  = 1.0f / 0.0327249f;
        const float inv2 = inv * inv;
        const float sc[6] = {1.0f, inv, inv, inv2, inv2, inv2};
        int o = t / 8, j = t % 8, dy = o / 5, dx = o % 5;
        float v;
        if (j < 6)       v =  kern[j*25 + dy*5 + dx] * sc[j];
        else if (j == 6) v = -kern[1*25 + dy*5 + (4-dx)] * sc[1];
        else             v = -kern[2*25 + (4-dy)*5 + dx] * sc[2];
        ws[o*8 + j] = v;
    } else if (t < 279) {
        int p = t - 200;
        int arr, a, b;
        if (p < 12)       { arr=0; a=p;      b=24+p; }
        else if (p < 24)  { int i=p-12; arr=0; a=12+i; b=36+i; }
        else if (p == 24) { arr=1; a=0; b=2; }
        else if (p == 25) { arr=1; a=1; b=3; }
        else if (p < 38)  { int i=p-26; arr=2; a=i;    b=26+i; }
        else if (p < 50)  { int i=p-38; arr=2; a=13+i; b=39+i; }
        else if (p == 50) { arr=2; a=12; b=38; }
        else if (p == 51) { arr=2; a=25; b=51; }
        else if (p == 52) { arr=3; a=0; b=2; }
        else if (p == 53) { arr=3; a=1; b=3; }
        else if (p < 68)  { int i=p-54; arr=4; a=i; b=14+i; }
        else if (p == 68) { arr=5; a=0; b=1; }
        else {
            const signed char   A0[10] = {1,2,13,14,1,2,14,15,1,2};
            const signed char   A1[10] = {31,32,43,44,33,34,46,47,21,22};
            const unsigned char AR[10] = {0,0,0,0,2,2,2,2,4,4};
            int i = p - 69; arr = AR[i]; a = A0[i]; b = A1[i];
        }
        const float* bases[6] = {pw0, pb0, pw1, pb1, pwf, pbf};
        v2f v; v[0] = bases[arr][a]; v[1] = bases[arr][b];
        ((v2f*)(ws + 256))[p] = v;
    }
}

// One RHS eval fused with axpy: uout = ubase + alpha * rhs(uin).
// PACKED-FP32: conv packs the 2 input channels per v_pk_fma_f32; poly packs
// the 2 output heads k. 2 px/thread, 128-thread blocks for 18 waves/CU.
// Per-pixel arithmetic identical to the 96x8 version (bit-exact).
__global__ __launch_bounds__(128, 5) void rhs_kernel(
    const float* __restrict__ uin,
    const float* __restrict__ ubase,
    float* __restrict__ uout,
    const float* __restrict__ ws,
    float alpha)
{
    const float* K8T = ws;
    const v2f* PP = (const v2f*)(ws + 256);

    __shared__ v2f sh[SH2][SW];
    const int b   = blockIdx.z;
    const int ty0 = blockIdx.y * TILEY;
    const int tx0 = blockIdx.x * TILEX;
    const int tid = threadIdx.x;
    const size_t bo = (size_t)b * 2 * PLANE;

    // ---- Staging: 432 sites (both channels per site), 3-4 iters/thread.
    const float* uin_b = uin + bo;
    for (int i = tid; i < NSITE; i += 128) {
        const int ly  = i / SW;
        const int col = i - ly * SW;
        int gy = ty0 + ly - 2;  if (gy < 0) gy += HH; else if (gy >= HH) gy -= HH;
        int gx = tx0 + col - 2; if (gx < 0) gx += WW; else if (gx >= WW) gx -= WW;
        const int gi = gy*WW + gx;
        v2f v; v[0] = uin_b[gi]; v[1] = uin_b[PLANE + gi];
        sh[ly][col] = v;
    }
    __syncthreads();

    const int cy = tid >> 4;            // 0..7
    const int x2 = (tid & 15) * 2;      // 0,2,..,30

    // ---- Conv: D2[px][j] = v2f over channels. dy loop rolled (code size).
    v2f D2[2][8];
    #pragma unroll
    for (int p = 0; p < 2; ++p)
        #pragma unroll
        for (int j = 0; j < 8; ++j)
            D2[p][j] = (v2f){0.0f, 0.0f};

    #pragma unroll 1
    for (int dy = 0; dy < 5; ++dy) {
        v2f row[6];
        #pragma unroll
        for (int dx = 0; dx < 6; ++dx)
            row[dx] = sh[cy + dy][x2 + dx];
        const float* Kt = K8T + dy * 40;   // 5 taps x 8 weights
        #pragma unroll
        for (int dx = 0; dx < 5; ++dx) {
            #pragma unroll
            for (int j = 0; j < 8; ++j) {
                const float w = Kt[dx*8 + j];
                D2[0][j] += row[dx]   * w;   // v_pk_fma_f32: both channels
                D2[1][j] += row[dx+1] * w;
            }
        }
    }

    // Feature i of pixel p: channel = i/6, map = i%6.
#define Z(p,i) (D2[p][(i)%6][(i)/6])

    v2f res[2];   // {k=0, k=1} per pixel
    #pragma unroll
    for (int p = 0; p < 2; ++p) {
        // ---- Base pass, packed over k (base features identical for both k).
        v2f o0 = PP[24], o1 = PP[25];
        #pragma unroll
        for (int i = 0; i < 12; ++i) {
            const float zv = Z(p, i);
            o0 += PP[i]    * zv;
            o1 += PP[12+i] * zv;
        }
        const v2f pb = o0 * o1;
        v2f q0 = PP[52] + PP[50]*pb;
        v2f q1 = PP[53] + PP[51]*pb;
        #pragma unroll
        for (int i = 0; i < 12; ++i) {
            const float zv = Z(p, i);
            q0 += PP[26+i] * zv;
            q1 += PP[38+i] * zv;
        }

        // ---- Gradients at the two upwind-selectable features, packed over k.
        const v2f t1 = o1*PP[69] + o0*PP[71];
        const v2f g1 = PP[77] + PP[66]*t1
            + PP[67]*(q1*(PP[73] + PP[50]*t1) + q0*(PP[75] + PP[51]*t1));
        const v2f t2 = o1*PP[70] + o0*PP[72];
        const v2f g2 = PP[78] + PP[66]*t2
            + PP[67]*(q1*(PP[74] + PP[50]*t2) + q0*(PP[76] + PP[51]*t2));

        // Selections (shared feature vector: all 4 replacements visible to both k).
        const float s1 = (g1[0] > 0.0f) ? Z(p,1) : D2[p][6][0];
        const float s2 = (g2[0] > 0.0f) ? Z(p,2) : D2[p][7][0];
        const float s3 = (g1[1] > 0.0f) ? Z(p,7) : D2[p][6][1];
        const float s4 = (g2[1] > 0.0f) ? Z(p,8) : D2[p][7][1];
#define XV(i) ((i)==1 ? s1 : (i)==2 ? s2 : (i)==7 ? s3 : (i)==8 ? s4 : Z(p,(i)))

        // ---- Forward poly at selected features, packed over k.
        v2f f0 = PP[24], f1 = PP[25];
        #pragma unroll
        for (int i = 0; i < 12; ++i) {
            const float xv = XV(i);
            f0 += PP[i]    * xv;
            f1 += PP[12+i] * xv;
        }
        const v2f pf = f0 * f1;
        v2f r0 = PP[52] + PP[50]*pf;
        v2f r1 = PP[53] + PP[51]*pf;
        v2f y  = PP[68] + PP[66]*pf;
        #pragma unroll
        for (int i = 0; i < 12; ++i) {
            const float xv = XV(i);
            r0 += PP[26+i] * xv;
            r1 += PP[38+i] * xv;
            y  += PP[54+i] * xv;
        }
        res[p] = y + PP[67]*(r0*r1);
#undef XV
    }

    const int oy = ty0 + cy, ox = tx0 + x2;
    const size_t o0i = bo + (size_t)oy * WW + ox;
    const float2 base0 = *(const float2*)(ubase + o0i);
    const float2 base1 = *(const float2*)(ubase + o0i + PLANE);
    float2 r0, r1;
    r0.x = base0.x + alpha * res[0][0];
    r0.y = base0.y + alpha * res[1][0];
    r1.x = base1.x + alpha * res[0][1];
    r1.y = base1.y + alpha * res[1][1];
    *(float2*)(uout + o0i)         = r0;
    *(float2*)(uout + o0i + PLANE) = r1;
}

extern "C" void kernel_launch(void* const* d_in, const int* in_sizes, int n_in,
                              void* d_out, int out_size, void* d_ws, size_t ws_size,
                              hipStream_t stream)
{
    const float* init = (const float*)d_in[0];
    const float* kern = (const float*)d_in[1];
    const float* pw0  = (const float*)d_in[2];
    const float* pb0  = (const float*)d_in[3];
    const float* pw1  = (const float*)d_in[4];
    const float* pb1  = (const float*)d_in[5];
    const float* pwf  = (const float*)d_in[6];
    const float* pbf  = (const float*)d_in[7];
    float* out = (float*)d_out;
    float* ws  = (float*)d_ws;

    float* bufA = ws + 512;            // NELEM floats: u_n
    float* bufH = bufA + NELEM;        // NELEM floats: u_half

    prep_kernel<<<dim3(1), dim3(320), 0, stream>>>(kern, pw0, pb0, pw1, pb1, pwf, pbf, ws);

    const dim3 grid(WW/TILEX, HH/TILEY, BATCH);   // (6, 24, 16) = 2304 blocks
    const dim3 block(128);
    const float DTF = 0.2f, DTH = 0.1f;

    // T=1 -> 5 RK2 (midpoint) steps, 2 RHS evals each (sequential dependency).
    rhs_kernel<<<grid, block, 0, stream>>>(init, init, bufH, ws, DTH);
    rhs_kernel<<<grid, block, 0, stream>>>(bufH, init, bufA, ws, DTF);
    for (int s = 0; s < 3; ++s) {
        rhs_kernel<<<grid, block, 0, stream>>>(bufA, bufA, bufH, ws, DTH);
        rhs_kernel<<<grid, block, 0, stream>>>(bufH, bufA, bufA, ws, DTF);
    }
    rhs_kernel<<<grid, block, 0, stream>>>(bufA, bufA, bufH, ws, DTH);
    rhs_kernel<<<grid, block, 0, stream>>>(bufH, bufA, out,  ws, DTF);
}